// Round 4
// baseline (217.259 us; speedup 1.0000x reference)
//
#include <hip/hip_runtime.h>
#include <cstdint>
#include <cstddef>

// DigitCapsule dynamic routing, fp32, b-per-lane layout, W staged in LDS.
// x[256,1152,8], W[1152,10,16,8], out v[256,10,16].
// vsum trick: logits at round r = votes . (v0+...+v_{r-1}).
constexpr int Bn = 256, In = 1152, Pn = 8, Jn = 10, Dn = 16;
constexpr int CA = 12, NCH = In / CA;  // capsA i-chunk, 96 chunks
constexpr int IB = 2;                  // capsB i's per block

// One-time transpose x[B][I*P] -> xT[I*P][B] so lane=b reads coalesce.
__global__ __launch_bounds__(256) void xpose(const float* __restrict__ x,
                                             float* __restrict__ xT) {
  __shared__ float tile[64][65];
  const int t = threadIdx.x, r = t >> 6, c = t & 63;
  const int ip0 = blockIdx.x * 64, b0 = blockIdx.y * 64;
  #pragma unroll
  for (int k = 0; k < 16; ++k) {
    const int row = k * 4 + r;
    tile[row][c] = x[(size_t)(b0 + row) * (In * Pn) + ip0 + c];
  }
  __syncthreads();
  #pragma unroll
  for (int k = 0; k < 16; ++k) {
    const int row = k * 4 + r;
    xT[(size_t)(ip0 + row) * Bn + b0 + c] = tile[c][row];
  }
}

// capsA: partial s[b,j,d] over an i-chunk. thread=b, block=(chunk, j).
// W staged in LDS once per block; read back as b128 broadcasts.
// MODE 0: c = 0.1 ; MODE 1: c from cbuf[j][i][b].
template <int MODE>
__global__ __launch_bounds__(256) void capsA(
    const float* __restrict__ xT, const float* __restrict__ w,
    const float* __restrict__ cbuf, float* __restrict__ spart) {
  __shared__ alignas(16) float wlds[CA * 128];  // 6 KB
  const int t = threadIdx.x, b = t, ch = blockIdx.x, j = blockIdx.y;
  const int i0 = ch * CA;

  // Stage W[i0..i0+CA-1][j][:][:] -> LDS. 1536 dwords, 6 per thread, coalesced.
  {
    const float* wbase = w + ((size_t)i0 * Jn + j) * 128;
    #pragma unroll
    for (int k = 0; k < 6; ++k) {
      const int e = t + k * 256;
      const int row = e >> 7, col = e & 127;
      wlds[e] = wbase[(size_t)row * (Jn * 128) + col];
    }
  }
  __syncthreads();

  float s[Dn];
  #pragma unroll
  for (int d = 0; d < Dn; ++d) s[d] = 0.f;

  for (int ii = 0; ii < CA; ++ii) {
    const int i = i0 + ii;
    const float* xr = xT + (size_t)i * (Pn * Bn) + b;
    float xc[Pn];
    #pragma unroll
    for (int p = 0; p < Pn; ++p) xc[p] = xr[p * Bn];
    float c = 0.1f;
    if (MODE) c = cbuf[((size_t)j * In + i) * Bn + b];
    #pragma unroll
    for (int p = 0; p < Pn; ++p) xc[p] *= c;

    const float4* wf = (const float4*)&wlds[ii * 128];
    #pragma unroll
    for (int d = 0; d < Dn; ++d) {
      const float4 w0 = wf[d * 2];      // ds_read_b128 broadcast
      const float4 w1 = wf[d * 2 + 1];
      float dot = w0.x * xc[0];
      dot = fmaf(w0.y, xc[1], dot); dot = fmaf(w0.z, xc[2], dot);
      dot = fmaf(w0.w, xc[3], dot); dot = fmaf(w1.x, xc[4], dot);
      dot = fmaf(w1.y, xc[5], dot); dot = fmaf(w1.z, xc[6], dot);
      dot = fmaf(w1.w, xc[7], dot);
      s[d] += dot;
    }
  }
  float* sp = spart + (((size_t)ch * Jn + j) * Dn) * Bn + b;
  #pragma unroll
  for (int d = 0; d < Dn; ++d) sp[d * Bn] = s[d];
}

// capsF: reduce 96 chunk-partials, squash.
// MODE 0: vsumT = v ; MODE 1: vsumT += v ; MODE 2: out[b][j][d] = v.
template <int MODE>
__global__ __launch_bounds__(256) void capsF(
    const float* __restrict__ spart, float* __restrict__ vsumT,
    float* __restrict__ out) {
  __shared__ float red[4][64][17];
  const int t = threadIdx.x, bl = t & 63, cg = t >> 6;
  const int j = blockIdx.x, b = blockIdx.y * 64 + bl;
  float s[Dn];
  #pragma unroll
  for (int d = 0; d < Dn; ++d) s[d] = 0.f;
  for (int ch = cg; ch < NCH; ch += 4) {
    const float* sp = spart + (((size_t)ch * Jn + j) * Dn) * Bn + b;
    #pragma unroll
    for (int d = 0; d < Dn; ++d) s[d] += sp[d * Bn];
  }
  #pragma unroll
  for (int d = 0; d < Dn; ++d) red[cg][bl][d] = s[d];
  __syncthreads();
  if (t < 64) {
    float v[Dn], n2 = 0.f;
    #pragma unroll
    for (int d = 0; d < Dn; ++d) {
      const float z = red[0][bl][d] + red[1][bl][d] + red[2][bl][d] + red[3][bl][d];
      v[d] = z;
      n2 = fmaf(z, z, n2);
    }
    const float sc = n2 / (1.f + n2) / sqrtf(n2 + 1e-7f);
    if (MODE == 2) {
      float* o = out + ((size_t)b * Jn + j) * Dn;
      #pragma unroll
      for (int d = 0; d < Dn; ++d) o[d] = v[d] * sc;
    } else if (MODE == 1) {
      #pragma unroll
      for (int d = 0; d < Dn; ++d) vsumT[((size_t)j * Dn + d) * Bn + b] += v[d] * sc;
    } else {
      #pragma unroll
      for (int d = 0; d < Dn; ++d) vsumT[((size_t)j * Dn + d) * Bn + b] = v[d] * sc;
    }
  }
}

// capsB: logits l[j] = sum_d vote(b,i,j,d)*vsum[b,j,d]; c = softmax_j.
// thread=b, block = IB i's. W staged in LDS; vsum hoisted per j across the IB i's.
__global__ __launch_bounds__(256) void capsB(
    const float* __restrict__ xT, const float* __restrict__ w,
    const float* __restrict__ vsumT, float* __restrict__ cbuf) {
  __shared__ alignas(16) float wlds[IB * 1280];  // 10 KB
  const int t = threadIdx.x, b = t;
  const int i0 = blockIdx.x * IB;

  // Stage W[i0..i0+IB-1] (contiguous 1280 dwords each), coalesced.
  {
    const float* wbase = w + (size_t)i0 * 1280;
    #pragma unroll
    for (int k = 0; k < IB * 5; ++k) wlds[t + k * 256] = wbase[t + k * 256];
  }
  __syncthreads();

  float xv[IB][Pn];
  #pragma unroll
  for (int ii = 0; ii < IB; ++ii) {
    const float* xr = xT + (size_t)(i0 + ii) * (Pn * Bn) + b;
    #pragma unroll
    for (int p = 0; p < Pn; ++p) xv[ii][p] = xr[p * Bn];
  }

  float l[IB][Jn];
  for (int j = 0; j < Jn; ++j) {
    float v16[Dn];
    #pragma unroll
    for (int d = 0; d < Dn; ++d) v16[d] = vsumT[((size_t)j * Dn + d) * Bn + b];
    #pragma unroll
    for (int ii = 0; ii < IB; ++ii) {
      const float4* wf = (const float4*)&wlds[ii * 1280 + j * 128];
      float acc = 0.f;
      #pragma unroll
      for (int d = 0; d < Dn; ++d) {
        const float4 w0 = wf[d * 2];
        const float4 w1 = wf[d * 2 + 1];
        float dot = w0.x * xv[ii][0];
        dot = fmaf(w0.y, xv[ii][1], dot); dot = fmaf(w0.z, xv[ii][2], dot);
        dot = fmaf(w0.w, xv[ii][3], dot); dot = fmaf(w1.x, xv[ii][4], dot);
        dot = fmaf(w1.y, xv[ii][5], dot); dot = fmaf(w1.z, xv[ii][6], dot);
        dot = fmaf(w1.w, xv[ii][7], dot);
        acc = fmaf(dot, v16[d], acc);
      }
      l[ii][j] = acc;
    }
  }

  #pragma unroll
  for (int ii = 0; ii < IB; ++ii) {
    float m = l[ii][0];
    #pragma unroll
    for (int j = 1; j < Jn; ++j) m = fmaxf(m, l[ii][j]);
    float ssum = 0.f;
    #pragma unroll
    for (int j = 0; j < Jn; ++j) { l[ii][j] = __expf(l[ii][j] - m); ssum += l[ii][j]; }
    const float inv = 1.f / ssum;
    #pragma unroll
    for (int j = 0; j < Jn; ++j)
      cbuf[((size_t)j * In + (i0 + ii)) * Bn + b] = l[ii][j] * inv;
  }
}

extern "C" void kernel_launch(void* const* d_in, const int* in_sizes, int n_in,
                              void* d_out, int out_size, void* d_ws, size_t ws_size,
                              hipStream_t stream) {
  const float* x = (const float*)d_in[0];  // [256,1152,8]
  const float* w = (const float*)d_in[1];  // [1152,10,16,8]
  float* xT    = (float*)d_ws;                      // [I*P][B]   9.44 MB
  float* cbuf  = xT + (size_t)In * Pn * Bn;         // [J][I][B] 11.80 MB
  float* vsumT = cbuf + (size_t)Jn * In * Bn;       // [J][D][B]  0.16 MB
  float* spart = vsumT + (size_t)Jn * Dn * Bn;      // [NCH][J][D][B] 15.73 MB
  float* out = (float*)d_out;                       // [256,10,16]

  xpose<<<dim3((In * Pn) / 64, Bn / 64), 256, 0, stream>>>(x, xT);

  capsA<0><<<dim3(NCH, Jn), 256, 0, stream>>>(xT, w, nullptr, spart);
  capsF<0><<<dim3(Jn, 4), 256, 0, stream>>>(spart, vsumT, out);   // vsum = v0

  capsB<<<In / IB, 256, 0, stream>>>(xT, w, vsumT, cbuf);         // c1
  capsA<1><<<dim3(NCH, Jn), 256, 0, stream>>>(xT, w, cbuf, spart);
  capsF<1><<<dim3(Jn, 4), 256, 0, stream>>>(spart, vsumT, out);   // vsum += v1

  capsB<<<In / IB, 256, 0, stream>>>(xT, w, vsumT, cbuf);         // c2
  capsA<1><<<dim3(NCH, Jn), 256, 0, stream>>>(xT, w, cbuf, spart);
  capsF<2><<<dim3(Jn, 4), 256, 0, stream>>>(spart, vsumT, out);   // out = v2
}